// Round 6
// baseline (897.924 us; speedup 1.0000x reference)
//
#include <hip/hip_runtime.h>

#define S_LEN 2048
#define DMODEL 1024
#define NBATCH 4

typedef unsigned short u16;
typedef __bf16 bf16x8 __attribute__((ext_vector_type(8)));
typedef float f32x4 __attribute__((ext_vector_type(4)));

typedef __attribute__((address_space(3))) unsigned lds_u32;
typedef const __attribute__((address_space(1))) unsigned glb_u32;

__device__ __forceinline__ u16 f2bf(float f) {
  union { float f; unsigned u; } v;
  v.f = f;
  unsigned r = v.u + 0x7fffu + ((v.u >> 16) & 1u);
  return (u16)(r >> 16);
}

__device__ __forceinline__ float bf2f(u16 h) {
  union { unsigned u; float f; } v;
  v.u = ((unsigned)h) << 16;
  return v.f;
}

// ---------------- convert x: fp32 -> bf16, flat ----------------
__global__ void convert_x_kernel(const float* __restrict__ x, u16* __restrict__ xb, long n) {
  long i = ((long)blockIdx.x * blockDim.x + threadIdx.x) * 4;
  long stride = (long)gridDim.x * blockDim.x * 4;
  for (; i < n; i += stride) {
    float4 v = *reinterpret_cast<const float4*>(x + i);
    ushort4 o;
    o.x = f2bf(v.x); o.y = f2bf(v.y); o.z = f2bf(v.z); o.w = f2bf(v.w);
    *reinterpret_cast<ushort4*>(xb + i) = o;
  }
}

// ---------------- transpose-convert W: Wt[n][k] = bf16(W[k][n]), 1024x1024 ----------------
__global__ void transpose_w_kernel(const float* __restrict__ W, u16* __restrict__ Wt) {
  __shared__ float tile[32][33];
  int tx = threadIdx.x, ty = threadIdx.y;
  int k0 = blockIdx.x * 32, n0 = blockIdx.y * 32;
#pragma unroll
  for (int i = 0; i < 32; i += 8)
    tile[ty + i][tx] = W[(long)(k0 + ty + i) * DMODEL + n0 + tx];
  __syncthreads();
#pragma unroll
  for (int i = 0; i < 32; i += 8)
    Wt[(long)(n0 + ty + i) * DMODEL + k0 + tx] = f2bf(tile[tx][ty + i]);
}

// ================= 256xBN NT GEMM, BK=32, 64 KiB LDS (2 blocks/CU) =================
// C[M][N] = A[M][K] * B[N][K]^T. BM=256, BN in {256,128}, BK=32, 512 thr = 8 waves (2Mx4N).
// LDS: buf{0,1} x (A 16KB | B 16|8KB) at 32KB stride, 1024B subtiles [16r][32c] bf16,
// st_16x32 swizzle (inner ^= ((inner>>9)&1)<<5); staged linear via global_load_lds from
// inverse-swizzled global source; reads apply the same involution (frag_off).
// One K-tile per iteration: stage tile g+1 -> buf^1 (3-4 loads/thread), read all frags
// of tile g (8-12 b128), lgkmcnt(0), 16*NQN*2 MFMA, vmcnt(0), one barrier.
// WAR: buf^1's last readers drained at tile g-1's lgkmcnt(0), >=1 barrier before this
// tile's STG. RAW: vmcnt(0) before the closing barrier -> tile g+1 resident.
// Stall coverage comes from the co-resident second block (64 KiB LDS -> 2 blocks/CU).
// CMODE: 0 = f32 row-major; 1 = bf16 row-major; 3 = fused QKV epilogue (BN=256 only)
// CAUSAL: 0 none; 1 skip bn>bm; 2 Keff=(bm+1)*256

template<int CMODE, int CAUSAL, int BN>
__global__ __launch_bounds__(512, 4) void gemm256(
    const u16* __restrict__ A, const u16* __restrict__ B, void* __restrict__ Cptr,
    int lda, int ldb, int ldc, int Kdim,
    long sAz, long sBz, long sCz)
{
  constexpr int NQN = BN / 128;   // B 128-col quadrants
  int bm = blockIdx.x, bn = blockIdx.y, bz = blockIdx.z;
  if (CAUSAL == 1 && bn > bm) return;
  int Keff = Kdim;
  if (CAUSAL == 2) { int lim = (bm + 1) * 256; if (lim < Keff) Keff = lim; }
  int NT = Keff >> 5;   // K-tiles of 32

  const u16* Ab = A + (long)bz * sAz + (long)bm * 256 * lda;
  const u16* Bb = B + (long)bz * sBz + (long)bn * BN * ldb;

  __shared__ char lds[65536];

  int tid = threadIdx.x;
  int lane = tid & 63, w = tid >> 6;
  int wm = w >> 2, wn = w & 3;
  int l15 = lane & 15, lhi = lane >> 4;
  // fragment read offset within a 1024B subtile (st_16x32 swizzled)
  int frag_off = (l15 * 64 + lhi * 16) ^ (((lane >> 3) & 1) << 5);

  // staging source pre-swizzle: lane's linear 16B LDS chunk <- logical chunk (lane ^ hi-bit-pair)
  int le = lane ^ ((lane >> 5) << 1);
  int lr = le >> 2;          // row within 16-row subtile
  int kb = (le & 3) * 8;     // k-element offset within 32-col subtile

  const u16* Asrc = Ab + (long)(w * 16 + lr) * lda + kb;
  const u16* Bsrc = Bb + (long)(w * 16 + lr) * ldb + kb;

  // stage tile T into buffer BUFB. A: 256 rows = 2 gloads (halves at rows +0,+128).
  // B: BN rows = 2 gloads (BN=256) or 1 (BN=128). Wave w stages subtile(s) w (+8).
#define STG_A(T, BUFB) do { \
    const u16* _s = Asrc + (T) * 32; \
    char* _d = lds + (BUFB) * 32768 + w * 1024; \
    __builtin_amdgcn_global_load_lds((glb_u32*)_s, (lds_u32*)_d, 16, 0, 0); \
    __builtin_amdgcn_global_load_lds((glb_u32*)(_s + (long)128 * lda), (lds_u32*)(_d + 8192), 16, 0, 0); \
  } while (0)
#define STG_B(T, BUFB) do { \
    const u16* _s = Bsrc + (T) * 32; \
    char* _d = lds + (BUFB) * 32768 + 16384 + w * 1024; \
    __builtin_amdgcn_global_load_lds((glb_u32*)_s, (lds_u32*)_d, 16, 0, 0); \
    if (BN == 256) \
      __builtin_amdgcn_global_load_lds((glb_u32*)(_s + (long)128 * ldb), (lds_u32*)(_d + 8192), 16, 0, 0); \
  } while (0)

  f32x4 acc[2][NQN][4][2];
#pragma unroll
  for (int a = 0; a < 2; ++a)
#pragma unroll
    for (int b = 0; b < NQN; ++b)
#pragma unroll
      for (int c = 0; c < 4; ++c)
#pragma unroll
        for (int d = 0; d < 2; ++d)
          acc[a][b][c][d] = (f32x4){0.f, 0.f, 0.f, 0.f};

  // prologue: tile 0 resident
  STG_A(0, 0); STG_B(0, 0);
  asm volatile("s_waitcnt vmcnt(0)" ::: "memory");
  __builtin_amdgcn_s_barrier();

  for (int g = 0; g < NT; ++g) {
    int buf = g & 1;
    if (g + 1 < NT) { STG_A(g + 1, buf ^ 1); STG_B(g + 1, buf ^ 1); }

    const char* _Al = lds + buf * 32768;
    const char* _Bl = _Al + 16384;
    bf16x8 a0[4], a1[4], bq[NQN][2];
#pragma unroll
    for (int i = 0; i < 4; ++i)
      a0[i] = *(const bf16x8*)(_Al + (wm * 4 + i) * 1024 + frag_off);
#pragma unroll
    for (int qn = 0; qn < NQN; ++qn)
#pragma unroll
      for (int j = 0; j < 2; ++j)
        bq[qn][j] = *(const bf16x8*)(_Bl + (qn * 8 + wn * 2 + j) * 1024 + frag_off);
#pragma unroll
    for (int i = 0; i < 4; ++i)
      a1[i] = *(const bf16x8*)(_Al + (8 + wm * 4 + i) * 1024 + frag_off);

    asm volatile("s_waitcnt lgkmcnt(0)" ::: "memory");
    __builtin_amdgcn_sched_barrier(0);
    __builtin_amdgcn_s_setprio(1);
#pragma unroll
    for (int i = 0; i < 4; ++i)
#pragma unroll
      for (int qn = 0; qn < NQN; ++qn)
#pragma unroll
        for (int j = 0; j < 2; ++j)
          acc[0][qn][i][j] = __builtin_amdgcn_mfma_f32_16x16x32_bf16(a0[i], bq[qn][j], acc[0][qn][i][j], 0, 0, 0);
#pragma unroll
    for (int i = 0; i < 4; ++i)
#pragma unroll
      for (int qn = 0; qn < NQN; ++qn)
#pragma unroll
        for (int j = 0; j < 2; ++j)
          acc[1][qn][i][j] = __builtin_amdgcn_mfma_f32_16x16x32_bf16(a1[i], bq[qn][j], acc[1][qn][i][j], 0, 0, 0);
    __builtin_amdgcn_s_setprio(0);

    asm volatile("s_waitcnt vmcnt(0)" ::: "memory");   // tile g+1 resident (free on last iter)
    __builtin_amdgcn_s_barrier();
  }
#undef STG_A
#undef STG_B

  // epilogue: C/D frag mapping: row = base + lhi*4 + reg, col = base + l15
  int Mbase = bm * 256, Nbase = bn * BN;
#pragma unroll
  for (int qm = 0; qm < 2; ++qm)
#pragma unroll
    for (int qn = 0; qn < NQN; ++qn)
#pragma unroll
      for (int i = 0; i < 4; ++i)
#pragma unroll
        for (int j = 0; j < 2; ++j) {
          int r0 = Mbase + qm * 128 + wm * 64 + i * 16 + lhi * 4;
          int col = Nbase + qn * 128 + wn * 32 + j * 16 + l15;
          f32x4 v = acc[qm][qn][i][j];
          if constexpr (CMODE == 0) {
            float* C = (float*)Cptr + (long)bz * sCz;
#pragma unroll
            for (int r = 0; r < 4; ++r)
              C[(long)(r0 + r) * ldc + col] = v[r];
          } else if constexpr (CMODE == 1) {
            u16* C = (u16*)Cptr + (long)bz * sCz;
#pragma unroll
            for (int r = 0; r < 4; ++r)
              C[(long)(r0 + r) * ldc + col] = f2bf(v[r]);
          } else {
            // fused QKV: cols [0,1024)=Q, [1024,2048)=K row-major bf16; [2048,3072)=V -> Vt[b][e][s]
            if (col < 2048) {
              u16* dst = (u16*)Cptr + (col >= 1024 ? 8388608 : 0);
              int c = col & 1023;
#pragma unroll
              for (int r = 0; r < 4; ++r)
                dst[(long)(r0 + r) * 1024 + c] = f2bf(v[r]);
            } else {
              u16* Vt = (u16*)Cptr + 16777216;
              int e = col - 2048;
              int bb = r0 >> 11, s = r0 & 2047;
              ushort4 u;
              u.x = f2bf(v[0]); u.y = f2bf(v[1]); u.z = f2bf(v[2]); u.w = f2bf(v[3]);
              *reinterpret_cast<ushort4*>(Vt + ((long)bb * 1024 + e) * 2048 + s) = u;
            }
          }
        }
}

// ---------------- one-pass causal row softmax: sc(bf16, unscaled) -> P(bf16) ----------------
__global__ __launch_bounds__(256) void softmax1p(const u16* __restrict__ sc,
                                                 u16* __restrict__ P) {
  int q = blockIdx.x, b = blockIdx.y;
  const u16* srow = sc + ((long)b * S_LEN + q) * S_LEN;
  u16* prow = P + ((long)b * S_LEN + q) * S_LEN;
  int n = q + 1;
  int nz = ((q >> 8) + 1) << 8;   // zero-fill bound (256-aligned)
  int tid = threadIdx.x;
  int j0 = tid * 8;
  const float scale = 0.03125f;   // 1/sqrt(1024)

  __shared__ float red[8];

  float vs[8];
#pragma unroll
  for (int e = 0; e < 8; ++e) vs[e] = -1e30f;
  if (j0 < n) {
    ushort4 a = *reinterpret_cast<const ushort4*>(srow + j0);
    ushort4 c = *reinterpret_cast<const ushort4*>(srow + j0 + 4);
    vs[0] = bf2f(a.x) * scale; vs[1] = bf2f(a.y) * scale;
    vs[2] = bf2f(a.z) * scale; vs[3] = bf2f(a.w) * scale;
    vs[4] = bf2f(c.x) * scale; vs[5] = bf2f(c.y) * scale;
    vs[6] = bf2f(c.z) * scale; vs[7] = bf2f(c.w) * scale;
#pragma unroll
    for (int e = 0; e < 8; ++e)
      if (j0 + e >= n) vs[e] = -1e30f;
  }

  float m = -1e30f;
#pragma unroll
  for (int e = 0; e < 8; ++e) m = fmaxf(m, vs[e]);
#pragma unroll
  for (int off = 32; off > 0; off >>= 1) m = fmaxf(m, __shfl_xor(m, off, 64));
  if ((tid & 63) == 0) red[tid >> 6] = m;
  __syncthreads();
  float ms = fmaxf(fmaxf(red[0], red[1]), fmaxf(red[2], red[3]));

  float p[8];
  float s = 0.f;
#pragma unroll
  for (int e = 0; e < 8; ++e) { p[e] = __expf(vs[e] - ms); s += (j0 + e < n) ? p[e] : 0.f; }
#pragma unroll
  for (int off = 32; off > 0; off >>= 1) s += __shfl_xor(s, off, 64);
  __syncthreads();
  if ((tid & 63) == 0) red[4 + (tid >> 6)] = s;
  __syncthreads();
  float inv = 1.f / (red[4] + red[5] + red[6] + red[7]);

  if (j0 < nz) {
    ushort4 o0, o1;
    o0.x = (j0 + 0 < n) ? f2bf(p[0] * inv) : (u16)0;
    o0.y = (j0 + 1 < n) ? f2bf(p[1] * inv) : (u16)0;
    o0.z = (j0 + 2 < n) ? f2bf(p[2] * inv) : (u16)0;
    o0.w = (j0 + 3 < n) ? f2bf(p[3] * inv) : (u16)0;
    o1.x = (j0 + 4 < n) ? f2bf(p[4] * inv) : (u16)0;
    o1.y = (j0 + 5 < n) ? f2bf(p[5] * inv) : (u16)0;
    o1.z = (j0 + 6 < n) ? f2bf(p[6] * inv) : (u16)0;
    o1.w = (j0 + 7 < n) ? f2bf(p[7] * inv) : (u16)0;
    *reinterpret_cast<ushort4*>(prow + j0) = o0;
    *reinterpret_cast<ushort4*>(prow + j0 + 4) = o1;
  }
}

// ---------------- launch ----------------
extern "C" void kernel_launch(void* const* d_in, const int* in_sizes, int n_in,
                              void* d_out, int out_size, void* d_ws, size_t ws_size,
                              hipStream_t stream) {
  const float* x  = (const float*)d_in[0];
  const float* Wq = (const float*)d_in[1];
  const float* Wk = (const float*)d_in[2];
  const float* Wv = (const float*)d_in[3];
  float* out = (float*)d_out;

  // workspace layout (bytes)
  char* ws = (char*)d_ws;
  u16* xb  = (u16*)(ws);                    // [8192][1024] bf16        : 16,777,216
  u16* wtb = (u16*)(ws + 16777216);         // [3072][1024] bf16 (W^T)  :  6,291,456
  u16* Qb  = (u16*)(ws + 23068672);         // [4][2048][1024] bf16     : 16,777,216
  u16* Kb  = (u16*)(ws + 39845888);         // [4][2048][1024] bf16
  u16* Vtb = (u16*)(ws + 56623104);         // [4][1024][2048] bf16
  u16* scb = (u16*)(ws + 73400320);         // [4][2048][2048] bf16     : 33,554,432
  u16* P   = (u16*)(ws + 106954752);        // [4][2048][2048] bf16     : 33,554,432

  long nx = (long)NBATCH * S_LEN * DMODEL;
  convert_x_kernel<<<2048, 256, 0, stream>>>(x, xb, nx);

  dim3 tb(32, 8);
  transpose_w_kernel<<<dim3(32, 32), tb, 0, stream>>>(Wq, wtb);
  transpose_w_kernel<<<dim3(32, 32), tb, 0, stream>>>(Wk, wtb + 1024 * 1024);
  transpose_w_kernel<<<dim3(32, 32), tb, 0, stream>>>(Wv, wtb + 2 * 1024 * 1024);

  // fused QKV projection: M=8192, N=3072 (Q|K|V), K=1024
  gemm256<3, 0, 256><<<dim3(32, 12, 1), 512, 0, stream>>>(
      xb, wtb, Qb, DMODEL, DMODEL, 0, DMODEL, 0, 0, 0);

  // scores (unscaled, bf16): per batch S = Q*K^T, causal block skip
  gemm256<1, 1, 256><<<dim3(8, 8, 4), 512, 0, stream>>>(
      Qb, Kb, scb, DMODEL, DMODEL, S_LEN, DMODEL,
      (long)S_LEN * DMODEL, (long)S_LEN * DMODEL, (long)S_LEN * S_LEN);

  softmax1p<<<dim3(S_LEN, NBATCH), 256, 0, stream>>>(scb, P);

  // O = P * V : A = P [2048][2048] bf16, B = Vt [1024][2048] bf16, K-limited, BN=128
  gemm256<0, 2, 128><<<dim3(8, 8, 4), 512, 0, stream>>>(
      P, Vtb, out, S_LEN, S_LEN, DMODEL, S_LEN,
      (long)S_LEN * S_LEN, (long)DMODEL * S_LEN, (long)S_LEN * DMODEL);
}

// Round 7
// 170.680 us; speedup vs baseline: 5.2608x; 5.2608x over previous
//
#include <hip/hip_runtime.h>

#define S_LEN 2048
#define DMODEL 1024
#define NBATCH 4

typedef unsigned short u16;
typedef __bf16 bf16x8 __attribute__((ext_vector_type(8)));
typedef float f32x4 __attribute__((ext_vector_type(4)));

typedef __attribute__((address_space(3))) unsigned lds_u32;
typedef const __attribute__((address_space(1))) unsigned glb_u32;

__device__ __forceinline__ u16 f2bf(float f) {
  union { float f; unsigned u; } v;
  v.f = f;
  unsigned r = v.u + 0x7fffu + ((v.u >> 16) & 1u);
  return (u16)(r >> 16);
}

__device__ __forceinline__ float bf2f(u16 h) {
  union { unsigned u; float f; } v;
  v.u = ((unsigned)h) << 16;
  return v.f;
}

// ---------------- convert x: fp32 -> bf16, flat ----------------
__global__ void convert_x_kernel(const float* __restrict__ x, u16* __restrict__ xb, long n) {
  long i = ((long)blockIdx.x * blockDim.x + threadIdx.x) * 4;
  long stride = (long)gridDim.x * blockDim.x * 4;
  for (; i < n; i += stride) {
    float4 v = *reinterpret_cast<const float4*>(x + i);
    ushort4 o;
    o.x = f2bf(v.x); o.y = f2bf(v.y); o.z = f2bf(v.z); o.w = f2bf(v.w);
    *reinterpret_cast<ushort4*>(xb + i) = o;
  }
}

// ---------------- transpose-convert W: Wt[n][k] = bf16(W[k][n]), 1024x1024 ----------------
__global__ void transpose_w_kernel(const float* __restrict__ W, u16* __restrict__ Wt) {
  __shared__ float tile[32][33];
  int tx = threadIdx.x, ty = threadIdx.y;
  int k0 = blockIdx.x * 32, n0 = blockIdx.y * 32;
#pragma unroll
  for (int i = 0; i < 32; i += 8)
    tile[ty + i][tx] = W[(long)(k0 + ty + i) * DMODEL + n0 + tx];
  __syncthreads();
#pragma unroll
  for (int i = 0; i < 32; i += 8)
    Wt[(long)(n0 + ty + i) * DMODEL + k0 + tx] = f2bf(tile[tx][ty + i]);
}

// ================= 256x256 NT GEMM, 4-phase/K-tile (r5 engine, unchanged) =================
// Used for scores only. See r5 comments for schedule proof.
#define STG(SRCP, LD, ISB, H, T, BUFB) do { \
    const u16* _s = (SRCP) + (long)(H) * 128 * (LD) + (T) * 64; \
    char* _d = lds + (BUFB) * 65536 + ((ISB) ? 32768 : 0) + ((H) * 8 + w) * 2048; \
    __builtin_amdgcn_global_load_lds((glb_u32*)_s, (lds_u32*)_d, 16, 0, 0); \
    __builtin_amdgcn_global_load_lds((glb_u32*)(_s + 32), (lds_u32*)(_d + 1024), 16, 0, 0); \
  } while (0)

#define READ_A(QM) do { \
    _Pragma("unroll") \
    for (int _i = 0; _i < 4; ++_i) { \
      int _mp = (QM) * 8 + wm * 4 + _i; \
      af[_i][0] = *(const bf16x8*)(_Al + (_mp * 2 + 0) * 1024 + frag_off); \
      af[_i][1] = *(const bf16x8*)(_Al + (_mp * 2 + 1) * 1024 + frag_off); \
    } \
  } while (0)

#define READ_BQ(DST, QN) do { \
    _Pragma("unroll") \
    for (int _j = 0; _j < 2; ++_j) { \
      int _np = (QN) * 8 + wn * 2 + _j; \
      DST[_j][0] = *(const bf16x8*)(_Bl + (_np * 2 + 0) * 1024 + frag_off); \
      DST[_j][1] = *(const bf16x8*)(_Bl + (_np * 2 + 1) * 1024 + frag_off); \
    } \
  } while (0)

#define MFMA16(QM, QN, BREG) do { \
    _Pragma("unroll") \
    for (int _i = 0; _i < 4; ++_i) \
      _Pragma("unroll") \
      for (int _j = 0; _j < 2; ++_j) { \
        acc[QM][QN][_i][_j] = __builtin_amdgcn_mfma_f32_16x16x32_bf16(af[_i][0], BREG[_j][0], acc[QM][QN][_i][_j], 0, 0, 0); \
        acc[QM][QN][_i][_j] = __builtin_amdgcn_mfma_f32_16x16x32_bf16(af[_i][1], BREG[_j][1], acc[QM][QN][_i][_j], 0, 0, 0); \
      } \
  } while (0)

template<int CMODE, int CAUSAL>
__global__ __launch_bounds__(512, 2) void gemm256(
    const u16* __restrict__ A, const u16* __restrict__ B, void* __restrict__ Cptr,
    int lda, int ldb, int ldc, int Kdim,
    long sAz, long sBz, long sCz)
{
  int bm = blockIdx.x, bn = blockIdx.y, bz = blockIdx.z;
  if (CAUSAL == 1 && bn > bm) return;
  int Keff = Kdim;
  if (CAUSAL == 2) { int lim = (bm + 1) * 256; if (lim < Keff) Keff = lim; }
  int NT = Keff >> 6;

  const u16* Ab = A + (long)bz * sAz + (long)bm * 256 * lda;
  const u16* Bb = B + (long)bz * sBz + (long)bn * 256 * ldb;

  __shared__ char lds[131072];

  int tid = threadIdx.x;
  int lane = tid & 63, w = tid >> 6;
  int wm = w >> 2, wn = w & 3;
  int l15 = lane & 15, lhi = lane >> 4;
  int frag_off = (l15 * 64 + lhi * 16) ^ (((lane >> 3) & 1) << 5);

  int le = lane ^ ((lane >> 5) << 1);
  int lr = le >> 2;
  int kb = (le & 3) * 8;

  const u16* Asrc = Ab + (long)(w * 16 + lr) * lda + kb;
  const u16* Bsrc = Bb + (long)(w * 16 + lr) * ldb + kb;

  f32x4 acc[2][2][4][2];
#pragma unroll
  for (int a = 0; a < 2; ++a)
#pragma unroll
    for (int b = 0; b < 2; ++b)
#pragma unroll
      for (int c = 0; c < 4; ++c)
#pragma unroll
        for (int d = 0; d < 2; ++d)
          acc[a][b][c][d] = (f32x4){0.f, 0.f, 0.f, 0.f};

  STG(Asrc, lda, 0, 0, 0, 0); STG(Bsrc, ldb, 1, 0, 0, 0);
  STG(Asrc, lda, 0, 1, 0, 0); STG(Bsrc, ldb, 1, 1, 0, 0);
  STG(Asrc, lda, 0, 0, 1, 1); STG(Bsrc, ldb, 1, 0, 1, 1);
  asm volatile("s_waitcnt vmcnt(4)" ::: "memory");
  __builtin_amdgcn_s_barrier();

  for (int g = 0; g < NT; ++g) {
    int buf = g & 1;
    int t1 = g + 1; if (t1 >= NT) t1 -= NT;
    int t2 = g + 2; if (t2 >= NT) t2 -= NT;
    const char* _Al = lds + buf * 65536;
    const char* _Bl = _Al + 32768;
    bf16x8 af[4][2], b0[2][2], b1[2][2];

    READ_A(0);
    READ_BQ(b0, 0);
    STG(Asrc, lda, 0, 1, t1, buf ^ 1);
    __builtin_amdgcn_s_barrier();
    asm volatile("s_waitcnt lgkmcnt(0)" ::: "memory");
    __builtin_amdgcn_sched_barrier(0);
    __builtin_amdgcn_s_setprio(1);
    MFMA16(0, 0, b0);
    __builtin_amdgcn_s_setprio(0);
    __builtin_amdgcn_s_barrier();

    READ_BQ(b1, 1);
    STG(Bsrc, ldb, 1, 1, t1, buf ^ 1);
    __builtin_amdgcn_s_barrier();
    asm volatile("s_waitcnt lgkmcnt(0)" ::: "memory");
    __builtin_amdgcn_sched_barrier(0);
    __builtin_amdgcn_s_setprio(1);
    MFMA16(0, 1, b1);
    __builtin_amdgcn_s_setprio(0);
    __builtin_amdgcn_s_barrier();

    READ_A(1);
    STG(Asrc, lda, 0, 0, t2, buf);
    __builtin_amdgcn_s_barrier();
    asm volatile("s_waitcnt lgkmcnt(0)" ::: "memory");
    __builtin_amdgcn_sched_barrier(0);
    __builtin_amdgcn_s_setprio(1);
    MFMA16(1, 1, b1);
    __builtin_amdgcn_s_setprio(0);
    __builtin_amdgcn_s_barrier();

    STG(Bsrc, ldb, 1, 0, t2, buf);
    __builtin_amdgcn_s_barrier();
    __builtin_amdgcn_s_setprio(1);
    MFMA16(1, 0, b0);
    __builtin_amdgcn_s_setprio(0);
    asm volatile("s_waitcnt vmcnt(4)" ::: "memory");
    __builtin_amdgcn_s_barrier();
  }

  int Mbase = bm * 256, Nbase = bn * 256;
#pragma unroll
  for (int qm = 0; qm < 2; ++qm)
#pragma unroll
    for (int qn = 0; qn < 2; ++qn)
#pragma unroll
      for (int i = 0; i < 4; ++i)
#pragma unroll
        for (int j = 0; j < 2; ++j) {
          int r0 = Mbase + qm * 128 + wm * 64 + i * 16 + lhi * 4;
          int col = Nbase + qn * 128 + wn * 32 + j * 16 + l15;
          f32x4 v = acc[qm][qn][i][j];
          if constexpr (CMODE == 0) {
            float* C = (float*)Cptr + (long)bz * sCz;
#pragma unroll
            for (int r = 0; r < 4; ++r)
              C[(long)(r0 + r) * ldc + col] = v[r];
          } else if constexpr (CMODE == 1) {
            u16* C = (u16*)Cptr + (long)bz * sCz;
#pragma unroll
            for (int r = 0; r < 4; ++r)
              C[(long)(r0 + r) * ldc + col] = f2bf(v[r]);
          }
        }
}

// ================= 128x256 NT GEMM, 2-phase/K-tile, depth-1 prefetch =================
// BM=128, BN=256, BK=64, 512 thr = 8 waves (2M x 4N), wave tile 64x64 (4x4 frags).
// LDS 96 KiB: buf{0,1} x (A 16KB | B 32KB) at 48KB stride. Same 1024B subtile +
// st_16x32 swizzle + inverse-swizzled staging as gemm256. All stages of tile g+1
// target buf^1 (never the buffer being read -> no wrap/WAR hazard, any NT>=2).
//   p0: read A(8 b128)+B(j0,1)(4); stage A(g+1)+Bh0(g+1) [4 gloads]; bar; lgkm; 16 MFMA; bar
//   p1: read B(j2,3)(4);           stage Bh1(g+1) [2 gloads];        bar; lgkm; 16 MFMA;
//       vmcnt(0) [tile g+1 resident]; bar
// CMODE: 0 = f32 row-major; 3 = fused QKV epilogue.  CAUSAL: 0 none; 2 Keff=(bm+1)*128.
template<int CMODE, int CAUSAL>
__global__ __launch_bounds__(512, 2) void gemm128(
    const u16* __restrict__ A, const u16* __restrict__ B, void* __restrict__ Cptr,
    int lda, int ldb, int ldc, int Kdim,
    long sAz, long sBz, long sCz)
{
  int bm = blockIdx.x, bn = blockIdx.y, bz = blockIdx.z;
  int Keff = Kdim;
  if (CAUSAL == 2) { int lim = (bm + 1) * 128; if (lim < Keff) Keff = lim; }
  int NT = Keff >> 6;   // >= 2 in all launches

  const u16* Ab = A + (long)bz * sAz + (long)bm * 128 * lda;
  const u16* Bb = B + (long)bz * sBz + (long)bn * 256 * ldb;

  __shared__ char lds[98304];

  int tid = threadIdx.x;
  int lane = tid & 63, w = tid >> 6;
  int wm = w >> 2, wn = w & 3;
  int l15 = lane & 15, lhi = lane >> 4;
  int frag_off = (l15 * 64 + lhi * 16) ^ (((lane >> 3) & 1) << 5);

  int le = lane ^ ((lane >> 5) << 1);
  int lr = le >> 2;
  int kb = (le & 3) * 8;

  const u16* Asrc = Ab + (long)(w * 16 + lr) * lda + kb;
  const u16* Bsrc = Bb + (long)(w * 16 + lr) * ldb + kb;

  // stage macros: wave w owns row-group w (A), row-groups w and 8+w (B)
#define STG_A1(T, BUFB) do { \
    const u16* _s = Asrc + (T) * 64; \
    char* _d = lds + (BUFB) * 49152 + w * 2048; \
    __builtin_amdgcn_global_load_lds((glb_u32*)_s, (lds_u32*)_d, 16, 0, 0); \
    __builtin_amdgcn_global_load_lds((glb_u32*)(_s + 32), (lds_u32*)(_d + 1024), 16, 0, 0); \
  } while (0)
#define STG_B1H0(T, BUFB) do { \
    const u16* _s = Bsrc + (T) * 64; \
    char* _d = lds + (BUFB) * 49152 + 16384 + w * 2048; \
    __builtin_amdgcn_global_load_lds((glb_u32*)_s, (lds_u32*)_d, 16, 0, 0); \
    __builtin_amdgcn_global_load_lds((glb_u32*)(_s + 32), (lds_u32*)(_d + 1024), 16, 0, 0); \
  } while (0)
#define STG_B1H1(T, BUFB) do { \
    const u16* _s = Bsrc + (long)128 * ldb + (T) * 64; \
    char* _d = lds + (BUFB) * 49152 + 16384 + (8 + w) * 2048; \
    __builtin_amdgcn_global_load_lds((glb_u32*)_s, (lds_u32*)_d, 16, 0, 0); \
    __builtin_amdgcn_global_load_lds((glb_u32*)(_s + 32), (lds_u32*)(_d + 1024), 16, 0, 0); \
  } while (0)

  f32x4 acc[4][4];
#pragma unroll
  for (int i = 0; i < 4; ++i)
#pragma unroll
    for (int j = 0; j < 4; ++j)
      acc[i][j] = (f32x4){0.f, 0.f, 0.f, 0.f};

  // prologue: tile0 -> buf0, drain
  STG_A1(0, 0); STG_B1H0(0, 0); STG_B1H1(0, 0);
  asm volatile("s_waitcnt vmcnt(0)" ::: "memory");
  __builtin_amdgcn_s_barrier();

  for (int g = 0; g < NT; ++g) {
    int buf = g & 1;
    const char* _Al = lds + buf * 49152;
    const char* _Bl = _Al + 16384;
    bf16x8 af[4][2], bfr[2][2];

    // ---- p0: n-frags 0,1 ----
#pragma unroll
    for (int i = 0; i < 4; ++i) {
      af[i][0] = *(const bf16x8*)(_Al + ((wm * 4 + i) * 2 + 0) * 1024 + frag_off);
      af[i][1] = *(const bf16x8*)(_Al + ((wm * 4 + i) * 2 + 1) * 1024 + frag_off);
    }
#pragma unroll
    for (int j = 0; j < 2; ++j) {
      bfr[j][0] = *(const bf16x8*)(_Bl + ((wn * 4 + j) * 2 + 0) * 1024 + frag_off);
      bfr[j][1] = *(const bf16x8*)(_Bl + ((wn * 4 + j) * 2 + 1) * 1024 + frag_off);
    }
    if (g + 1 < NT) { STG_A1(g + 1, buf ^ 1); STG_B1H0(g + 1, buf ^ 1); }
    __builtin_amdgcn_s_barrier();
    asm volatile("s_waitcnt lgkmcnt(0)" ::: "memory");
    __builtin_amdgcn_sched_barrier(0);
    __builtin_amdgcn_s_setprio(1);
#pragma unroll
    for (int i = 0; i < 4; ++i)
#pragma unroll
      for (int j = 0; j < 2; ++j) {
        acc[i][j] = __builtin_amdgcn_mfma_f32_16x16x32_bf16(af[i][0], bfr[j][0], acc[i][j], 0, 0, 0);
        acc[i][j] = __builtin_amdgcn_mfma_f32_16x16x32_bf16(af[i][1], bfr[j][1], acc[i][j], 0, 0, 0);
      }
    __builtin_amdgcn_s_setprio(0);
    __builtin_amdgcn_s_barrier();

    // ---- p1: n-frags 2,3 ----
#pragma unroll
    for (int j = 0; j < 2; ++j) {
      bfr[j][0] = *(const bf16x8*)(_Bl + ((wn * 4 + 2 + j) * 2 + 0) * 1024 + frag_off);
      bfr[j][1] = *(const bf16x8*)(_Bl + ((wn * 4 + 2 + j) * 2 + 1) * 1024 + frag_off);
    }
    if (g + 1 < NT) STG_B1H1(g + 1, buf ^ 1);
    __builtin_amdgcn_s_barrier();
    asm volatile("s_waitcnt lgkmcnt(0)" ::: "memory");
    __builtin_amdgcn_sched_barrier(0);
    __builtin_amdgcn_s_setprio(1);
#pragma unroll
    for (int i = 0; i < 4; ++i)
#pragma unroll
      for (int j = 0; j < 2; ++j) {
        acc[i][2 + j] = __builtin_amdgcn_mfma_f32_16x16x32_bf16(af[i][0], bfr[j][0], acc[i][2 + j], 0, 0, 0);
        acc[i][2 + j] = __builtin_amdgcn_mfma_f32_16x16x32_bf16(af[i][1], bfr[j][1], acc[i][2 + j], 0, 0, 0);
      }
    __builtin_amdgcn_s_setprio(0);
    asm volatile("s_waitcnt vmcnt(0)" ::: "memory");   // tile g+1 resident
    __builtin_amdgcn_s_barrier();
  }
#undef STG_A1
#undef STG_B1H0
#undef STG_B1H1

  int Mbase = bm * 128, Nbase = bn * 256;
#pragma unroll
  for (int i = 0; i < 4; ++i)
#pragma unroll
    for (int j = 0; j < 4; ++j) {
      int r0 = Mbase + wm * 64 + i * 16 + lhi * 4;
      int col = Nbase + wn * 64 + j * 16 + l15;
      f32x4 v = acc[i][j];
      if constexpr (CMODE == 0) {
        float* C = (float*)Cptr + (long)bz * sCz;
#pragma unroll
        for (int r = 0; r < 4; ++r)
          C[(long)(r0 + r) * ldc + col] = v[r];
      } else {
        // fused QKV: cols [0,1024)=Q, [1024,2048)=K row-major bf16; [2048,3072)=V -> Vt[b][e][s]
        if (col < 2048) {
          u16* dst = (u16*)Cptr + (col >= 1024 ? 8388608 : 0);
          int c = col & 1023;
#pragma unroll
          for (int r = 0; r < 4; ++r)
            dst[(long)(r0 + r) * 1024 + c] = f2bf(v[r]);
        } else {
          u16* Vt = (u16*)Cptr + 16777216;
          int e = col - 2048;
          int bb = r0 >> 11, s = r0 & 2047;
          ushort4 u;
          u.x = f2bf(v[0]); u.y = f2bf(v[1]); u.z = f2bf(v[2]); u.w = f2bf(v[3]);
          *reinterpret_cast<ushort4*>(Vt + ((long)bb * 1024 + e) * 2048 + s) = u;
        }
      }
    }
}

// ---------------- one-pass causal row softmax: sc(bf16, unscaled) -> P(bf16) ----------------
__global__ __launch_bounds__(256) void softmax1p(const u16* __restrict__ sc,
                                                 u16* __restrict__ P) {
  int q = blockIdx.x, b = blockIdx.y;
  const u16* srow = sc + ((long)b * S_LEN + q) * S_LEN;
  u16* prow = P + ((long)b * S_LEN + q) * S_LEN;
  int n = q + 1;
  int nz = ((q >> 8) + 1) << 8;
  int tid = threadIdx.x;
  int j0 = tid * 8;
  const float scale = 0.03125f;

  __shared__ float red[8];

  float vs[8];
#pragma unroll
  for (int e = 0; e < 8; ++e) vs[e] = -1e30f;
  if (j0 < n) {
    ushort4 a = *reinterpret_cast<const ushort4*>(srow + j0);
    ushort4 c = *reinterpret_cast<const ushort4*>(srow + j0 + 4);
    vs[0] = bf2f(a.x) * scale; vs[1] = bf2f(a.y) * scale;
    vs[2] = bf2f(a.z) * scale; vs[3] = bf2f(a.w) * scale;
    vs[4] = bf2f(c.x) * scale; vs[5] = bf2f(c.y) * scale;
    vs[6] = bf2f(c.z) * scale; vs[7] = bf2f(c.w) * scale;
#pragma unroll
    for (int e = 0; e < 8; ++e)
      if (j0 + e >= n) vs[e] = -1e30f;
  }

  float m = -1e30f;
#pragma unroll
  for (int e = 0; e < 8; ++e) m = fmaxf(m, vs[e]);
#pragma unroll
  for (int off = 32; off > 0; off >>= 1) m = fmaxf(m, __shfl_xor(m, off, 64));
  if ((tid & 63) == 0) red[tid >> 6] = m;
  __syncthreads();
  float ms = fmaxf(fmaxf(red[0], red[1]), fmaxf(red[2], red[3]));

  float p[8];
  float s = 0.f;
#pragma unroll
  for (int e = 0; e < 8; ++e) { p[e] = __expf(vs[e] - ms); s += (j0 + e < n) ? p[e] : 0.f; }
#pragma unroll
  for (int off = 32; off > 0; off >>= 1) s += __shfl_xor(s, off, 64);
  __syncthreads();
  if ((tid & 63) == 0) red[4 + (tid >> 6)] = s;
  __syncthreads();
  float inv = 1.f / (red[4] + red[5] + red[6] + red[7]);

  if (j0 < nz) {
    ushort4 o0, o1;
    o0.x = (j0 + 0 < n) ? f2bf(p[0] * inv) : (u16)0;
    o0.y = (j0 + 1 < n) ? f2bf(p[1] * inv) : (u16)0;
    o0.z = (j0 + 2 < n) ? f2bf(p[2] * inv) : (u16)0;
    o0.w = (j0 + 3 < n) ? f2bf(p[3] * inv) : (u16)0;
    o1.x = (j0 + 4 < n) ? f2bf(p[4] * inv) : (u16)0;
    o1.y = (j0 + 5 < n) ? f2bf(p[5] * inv) : (u16)0;
    o1.z = (j0 + 6 < n) ? f2bf(p[6] * inv) : (u16)0;
    o1.w = (j0 + 7 < n) ? f2bf(p[7] * inv) : (u16)0;
    *reinterpret_cast<ushort4*>(prow + j0) = o0;
    *reinterpret_cast<ushort4*>(prow + j0 + 4) = o1;
  }
}

// ---------------- launch ----------------
extern "C" void kernel_launch(void* const* d_in, const int* in_sizes, int n_in,
                              void* d_out, int out_size, void* d_ws, size_t ws_size,
                              hipStream_t stream) {
  const float* x  = (const float*)d_in[0];
  const float* Wq = (const float*)d_in[1];
  const float* Wk = (const float*)d_in[2];
  const float* Wv = (const float*)d_in[3];
  float* out = (float*)d_out;

  char* ws = (char*)d_ws;
  u16* xb  = (u16*)(ws);                    // [8192][1024] bf16
  u16* wtb = (u16*)(ws + 16777216);         // [3072][1024] bf16 (W^T)
  u16* Qb  = (u16*)(ws + 23068672);         // [4][2048][1024] bf16
  u16* Kb  = (u16*)(ws + 39845888);
  u16* Vtb = (u16*)(ws + 56623104);         // [4][1024][2048] bf16
  u16* scb = (u16*)(ws + 73400320);         // [4][2048][2048] bf16
  u16* P   = (u16*)(ws + 106954752);        // [4][2048][2048] bf16

  long nx = (long)NBATCH * S_LEN * DMODEL;
  convert_x_kernel<<<2048, 256, 0, stream>>>(x, xb, nx);

  dim3 tb(32, 8);
  transpose_w_kernel<<<dim3(32, 32), tb, 0, stream>>>(Wq, wtb);
  transpose_w_kernel<<<dim3(32, 32), tb, 0, stream>>>(Wk, wtb + 1024 * 1024);
  transpose_w_kernel<<<dim3(32, 32), tb, 0, stream>>>(Wv, wtb + 2 * 1024 * 1024);

  // fused QKV projection: M=8192, N=3072 (Q|K|V), K=1024 -> 768 blocks (3 exact rounds)
  gemm128<3, 0><<<dim3(64, 12, 1), 512, 0, stream>>>(
      xb, wtb, Qb, DMODEL, DMODEL, 0, DMODEL, 0, 0, 0);

  // scores (unscaled, bf16): per batch S = Q*K^T, causal block skip (r5 engine)
  gemm256<1, 1><<<dim3(8, 8, 4), 512, 0, stream>>>(
      Qb, Kb, scb, DMODEL, DMODEL, S_LEN, DMODEL,
      (long)S_LEN * DMODEL, (long)S_LEN * DMODEL, (long)S_LEN * S_LEN);

  softmax1p<<<dim3(S_LEN, NBATCH), 256, 0, stream>>>(scb, P);

  // O = P * V : BM=128 bands -> 256 blocks, longest block K=2048 at half M-work
  gemm128<0, 2><<<dim3(16, 4, 4), 512, 0, stream>>>(
      P, Vtb, out, S_LEN, S_LEN, DMODEL, S_LEN,
      (long)S_LEN * S_LEN, (long)DMODEL * S_LEN, (long)S_LEN * DMODEL);
}